// Round 5
// baseline (576.491 us; speedup 1.0000x reference)
//
#include <hip/hip_runtime.h>

// iRPE contextual/transposed PRODUCT, round-10: SPIN-SURFACED MEASUREMENT.
//
// r9 showed store issue is ~free (3x stores -> +15us ~= L2 rate) but the
// kernel dispatch still hides below the ~176-184us poison fills, so we have
// no direct counters. Two models fit everything:
//   A: kernel ~150us (2 TB/s, 3x off roofline -- 100us on the table)
//   B: kernel ~50us (at roofline; dur is dominated by harness dispatches)
// This round: production structure (fused, arithmetic buckets, plain 1x
// stores) + a THROUGHPUT-CALIBRATED independent-FMA spin (11264 fma/thread
// ~= +295us device-wide VALU) appended after the stores, DCE-protected via
// asm sink, seeded from lts data. Memory behavior untouched; the spin only
// stretches the dispatch window so rocprof surfaces OUR row.
//
// Pre-committed readout (kernel row now visible):
//  1. WRITE~262144KB, FETCH~17-35MB -> traffic ~290MB, floor ~46us; row dur
//     ~310-330 => mem hides under spin => attack store RATE next.
//  2. FETCH ~260-300MB -> RFO confirmed -> attack store cache policy next.
//  3. row dur ~450+ -> VALU/mem don't overlap -> issue coupling, specialize.

constexpr int cL  = 1024;
constexpr int cD  = 64;
constexpr int cK  = 49;
constexpr int cIT = 8;    // i rows per block

typedef float vf4 __attribute__((ext_vector_type(4)));

// piecewise_index(d) + BETA_INT for this config (verified absmax 0.0)
__device__ __forceinline__ int bucket_c(int d) {
    int a = d < 0 ? -d : d;
    int m = a < 4 ? a : 4;     // min(|d|,4)
    m -= (m >= 3) ? 1 : 0;     // q(|d|) = {0,1,2,2,3,3,...}
    int p = d < 0 ? -m : m;
    return p + 3;
}

__global__ __launch_bounds__(256) void irpe_fused_spin(
    const float* __restrict__ x,   // (bh, i, d)
    const float* __restrict__ W,   // (h, d, k)
    float*       __restrict__ out) // (bh, i, j)
{
    __shared__ vf4   xs4[cIT][cD / 4];
    __shared__ float lts[cIT * cK];

    const int gid = blockIdx.x;
    const int bh  = gid & 63;
    const int it  = gid >> 6;
    const int i0  = it * cIT;
    const int h   = bh & 7;
    const int tid = threadIdx.x;

    // ---- Phase A: stage 8 x rows (2 KB) ----
    if (tid < cIT * (cD / 4)) {
        const int li = tid >> 4;
        const int dq = tid & 15;
        xs4[li][dq] =
            ((const vf4*)x)[((size_t)bh * cL + (i0 + li)) * (cD / 4) + dq];
    }
    __syncthreads();

    // ---- Phase B: lt GEMV (same fmaf chain as r5-r9 -> identical bits) ----
    for (int p = tid; p < cIT * cK; p += 256) {
        const int li = p / cK;
        const int k  = p - li * cK;
        const float* wp = W + (size_t)h * cD * cK + k;
        const float* xr = (const float*)&xs4[li][0];
        float acc = 0.0f;
        #pragma unroll
        for (int d = 0; d < cD; ++d) acc = fmaf(xr[d], wp[(size_t)d * cK], acc);
        lts[p] = acc;
    }
    __syncthreads();

    // ---- Phase C: arithmetic buckets + single plain-store pass ----
    const int j0   = tid * 4;
    const int xj   = j0 & 31;
    const int yj   = j0 >> 5;
    const int yi   = i0 >> 5;
    const int xi0  = i0 & 31;
    const int rbase = 7 * bucket_c(yi - yj);
    const int base  = xi0 - xj;
    int cv[11];
    #pragma unroll
    for (int t = 0; t < 11; ++t) cv[t] = rbase + bucket_c(base + t - 3);

    vf4* obase = (vf4*)(out + ((size_t)bh * cL + i0) * cL);
    #pragma unroll
    for (int il = 0; il < cIT; ++il) {
        const float* lrow = lts + il * cK;
        vf4 o;
        o.x = lrow[cv[il + 3]];
        o.y = lrow[cv[il + 2]];
        o.z = lrow[cv[il + 1]];
        o.w = lrow[cv[il + 0]];
        obase[(size_t)il * (cL / 4) + tid] = o;
    }

    // ---- calibrated spin: 176 iters x 64 independent fma = 11264/thread ----
    // total = 8192blk x 4w x 11264 x 2cyc / 1024 SIMDs ~= 704K cyc ~= 295us.
    // Seeded from lts (runtime data, no constant folding); no fast-math, so
    // the affine fp chain cannot be collapsed. Sink keeps it live (rule #17).
    float a0 = lts[tid % 392] + 1.0f;
    float a1 = a0 * 1.125f,  a2 = a0 * 1.25f,  a3 = a0 * 1.375f;
    float a4 = a0 * 1.5f,    a5 = a0 * 1.625f, a6 = a0 * 1.75f, a7 = a0 * 1.875f;
    for (int s = 0; s < 176; ++s) {
        #pragma unroll
        for (int u = 0; u < 8; ++u) {
            a0 = fmaf(a0, 1.0000001f, 0.0625f);
            a1 = fmaf(a1, 1.0000002f, 0.0625f);
            a2 = fmaf(a2, 1.0000003f, 0.0625f);
            a3 = fmaf(a3, 1.0000004f, 0.0625f);
            a4 = fmaf(a4, 1.0000005f, 0.0625f);
            a5 = fmaf(a5, 1.0000006f, 0.0625f);
            a6 = fmaf(a6, 1.0000007f, 0.0625f);
            a7 = fmaf(a7, 1.0000008f, 0.0625f);
        }
    }
    asm volatile("" :: "v"(a0), "v"(a1), "v"(a2), "v"(a3),
                       "v"(a4), "v"(a5), "v"(a6), "v"(a7));
}

extern "C" void kernel_launch(void* const* d_in, const int* in_sizes, int n_in,
                              void* d_out, int out_size, void* d_ws, size_t ws_size,
                              hipStream_t stream) {
    const float* x   = (const float*)d_in[0];   // (8,8,1024,64) fp32
    const float* W   = (const float*)d_in[1];   // (8,64,49) fp32
    float*       out = (float*)d_out;           // (8,8,1024,1024) fp32

    irpe_fused_spin<<<64 * (cL / cIT), 256, 0, stream>>>(x, W, out);
}

// Round 6
// 390.506 us; speedup vs baseline: 1.4763x; 1.4763x over previous
//
#include <hip/hip_runtime.h>

// iRPE contextual/transposed PRODUCT, round-11: FILL-MIMIC PERSISTENT.
//
// r10 direct counters: FETCH 8.3MB (no RFO), WRITE 256MiB exact, LDS
// conflicts trivial, harness overhead calibrated at ~157us => baseline
// kernel ~145us for ~277MB = 1.9 TB/s, 3.3x off roofline. Eliminated so
// far: store decomposition, fused/split, nt/plain, RFO, LDS, issue rate.
// Remaining difference vs the 6.4 TB/s fill on this same chip: the fill
// runs ~3 waves/CU, each an endless contiguous store stream; we ran 23+
// waves/CU of short bursty block-lifetime streams. This round mimics the
// fill: 512 persistent blocks (2/CU, 25% occ), each marching ONE contiguous
// 512KB span linearly with double-buffered GEMV||store so the store pipe
// never idles and stores are never waited on.
//
// GEMV keeps the exact d-ascending fmaf chain (bit-identical, absmax 0.0);
// buckets arithmetic as verified in r6-r10.

constexpr int cL  = 1024;
constexpr int cD  = 64;
constexpr int cK  = 49;
constexpr int cKP = 52;    // padded lt row stride
constexpr int cCH = 16;    // rows per chunk (16-aligned => shared yi)
constexpr int cSEG = 128;  // rows per block
constexpr int cNCH = cSEG / cCH;   // 8 chunks

typedef float vf4 __attribute__((ext_vector_type(4)));

// piecewise_index(d) + BETA_INT for this config (verified absmax 0.0)
__device__ __forceinline__ int bucket_c(int d) {
    int a = d < 0 ? -d : d;
    int m = a < 4 ? a : 4;     // min(|d|,4)
    m -= (m >= 3) ? 1 : 0;     // q(|d|) = {0,1,2,2,3,3,...}
    int p = d < 0 ? -m : m;
    return p + 3;
}

__device__ __forceinline__ void gemv_chunk(
    const float* __restrict__ xsbuf,   // [cCH*cD] LDS
    float*       __restrict__ ltbuf,   // [cCH*cKP] LDS
    const float* __restrict__ W, int h, int tid)
{
    for (int p = tid; p < cCH * cK; p += 256) {     // 784 items
        const int li = p / cK;
        const int k  = p - li * cK;
        const float* wp = W + (size_t)h * cD * cK + k;
        const float* xr = xsbuf + li * cD;
        float acc = 0.0f;
        #pragma unroll
        for (int d = 0; d < cD; ++d)
            acc = fmaf(xr[d], wp[(size_t)d * cK], acc);
        ltbuf[li * cKP + k] = acc;
    }
}

__global__ __launch_bounds__(256) void irpe_persist(
    const float* __restrict__ x,   // (bh, i, d)
    const float* __restrict__ W,   // (h, d, k)
    float*       __restrict__ out) // (bh, i, j)
{
    __shared__ float xs[2][cCH * cD];    // 2 x 4 KB
    __shared__ float lts[2][cCH * cKP];  // 2 x 3.3 KB

    const int gid = blockIdx.x;          // 512 blocks
    const int bh  = gid & 63;
    const int seg = gid >> 6;            // 0..7
    const int i0  = seg * cSEG;
    const int h   = bh & 7;
    const int tid = threadIdx.x;

    // per-thread store-side constants
    const int j0 = tid * 4;
    const int xj = j0 & 31;
    const int yj = j0 >> 5;

    // x source for this block's 128 rows (vf4 granularity)
    const vf4* xsrc = (const vf4*)(x + ((size_t)bh * cL + i0) * cD);

    // ---- prologue: stage + GEMV chunk 0 ----
    ((vf4*)xs[0])[tid] = xsrc[tid];                  // 16 rows = 256 vf4
    __syncthreads();
    gemv_chunk(xs[0], lts[0], W, h, tid);
    __syncthreads();

    int cur = 0;
    for (int c = 0; c < cNCH; ++c) {
        // 1. prefetch next x chunk into registers (async, no wait yet)
        vf4 xn;
        const bool more = (c + 1 < cNCH);
        if (more) xn = xsrc[(c + 1) * 256 + tid];

        // 2. bucket tables for this chunk (rows share yi: 16-aligned run)
        const int i0c   = i0 + c * cCH;
        const int yi    = i0c >> 5;
        const int xi0   = i0c & 31;                  // 0 or 16
        const int rbase = 7 * bucket_c(yi - yj);
        int cv[cCH + 3];
        #pragma unroll
        for (int t = 0; t < cCH + 3; ++t)
            cv[t] = rbase + bucket_c(xi0 - xj + t - 3);

        // 3. store phase: 16 rows x 4 KB = 64 KB contiguous, plain stores,
        //    never waited on -- the block's single long write stream.
        vf4* obase = (vf4*)(out + ((size_t)bh * cL + i0c) * cL);
        const float* lbase = lts[cur];
        #pragma unroll
        for (int il = 0; il < cCH; ++il) {
            const float* lrow = lbase + il * cKP;
            vf4 o;
            o.x = lrow[cv[il + 3]];                  // cc = 0
            o.y = lrow[cv[il + 2]];                  // cc = 1
            o.z = lrow[cv[il + 1]];                  // cc = 2
            o.w = lrow[cv[il + 0]];                  // cc = 3
            obase[(size_t)il * (cL / 4) + tid] = o;
        }

        // 4. stage next x + GEMV it into the other lt buffer (overlaps
        //    the drain of the 64 KB just issued)
        if (more) {
            ((vf4*)xs[cur ^ 1])[tid] = xn;
            __syncthreads();
            gemv_chunk(xs[cur ^ 1], lts[cur ^ 1], W, h, tid);
            __syncthreads();
            cur ^= 1;
        }
    }
}

extern "C" void kernel_launch(void* const* d_in, const int* in_sizes, int n_in,
                              void* d_out, int out_size, void* d_ws, size_t ws_size,
                              hipStream_t stream) {
    const float* x   = (const float*)d_in[0];   // (8,8,1024,64) fp32
    const float* W   = (const float*)d_in[1];   // (8,64,49) fp32
    float*       out = (float*)d_out;           // (8,8,1024,1024) fp32

    const int grid = 64 * (cL / cSEG);          // 512 blocks = 2 per CU
    irpe_persist<<<grid, 256, 0, stream>>>(x, W, out);
}

// Round 7
// 286.284 us; speedup vs baseline: 2.0137x; 1.3640x over previous
//
#include <hip/hip_runtime.h>

// iRPE contextual/transposed PRODUCT, round-12: ZERO-WAIT WAVE STREAMING.
//
// r10/r11 synthesis: under r10's VALU spin the full 277 MB drained in ~50us
// (~5.5 TB/s) while r11's direct counters show waves 80% stalled at 1.6 TB/s
// => the HBM path is fine; the limiter is WAITING on stores. s_barrier
// forces s_waitcnt vmcnt(0), and any global load issued after stores forces
// a vmcnt wait that (in-order retirement) drains all older stores. Every
// r5-r11 variant had both. This round removes every in-loop vmcnt consumer:
//   - W[h][:,k] in 64 registers per lane (static-indexed, one-time load)
//   - wave's 32 x-rows pre-staged once into wave-PRIVATE LDS (no barriers)
//   - lt[i][k] lives in lane k's register; gather via __shfl (ds_bpermute,
//     lgkmcnt only); buckets arithmetic (verified bit-exact since r6)
//   - NO __syncthreads, NO global loads after prologue -> stores are
//     fire-and-forget until the end-of-kernel drain, like the 6.4 TB/s fill.
// GEMV keeps the exact d-ascending fmaf chain -> bit-identical output.

constexpr int cL = 1024;
constexpr int cD = 64;
constexpr int cK = 49;
constexpr int cRW = 32;   // rows per wave

typedef float vf4 __attribute__((ext_vector_type(4)));

// piecewise_index(d) + BETA_INT for this config (verified absmax 0.0)
__device__ __forceinline__ int bucket_c(int d) {
    int a = d < 0 ? -d : d;
    int m = a < 4 ? a : 4;     // min(|d|,4)
    m -= (m >= 3) ? 1 : 0;     // q(|d|) = {0,1,2,2,3,3,...}
    int p = d < 0 ? -m : m;
    return p + 3;
}

__global__ __launch_bounds__(256) void irpe_wavestream(
    const float* __restrict__ x,   // (bh, i, d)
    const float* __restrict__ W,   // (h, d, k)
    float*       __restrict__ out) // (bh, i, j)
{
    __shared__ float xw[4][cRW * cD];    // 4 waves x 8 KB, wave-private

    const int gid  = blockIdx.x;         // 512 blocks = 2/CU
    const int bh   = gid & 63;
    const int segq = gid >> 6;           // 0..7
    const int tid  = threadIdx.x;
    const int w    = tid >> 6;           // wave 0..3
    const int lane = tid & 63;
    const int i0w  = segq * 128 + w * cRW;
    const int h    = bh & 7;

    // ---- one-time: this lane's W column into registers ----
    const int klane = lane < cK ? lane : lane - cK;   // lanes 49-63: dup k
    float wreg[cD];
    const float* wcol = W + (size_t)h * cD * cK + klane;
    #pragma unroll
    for (int d = 0; d < cD; ++d) wreg[d] = wcol[(size_t)d * cK];

    // ---- one-time: stage this wave's 32 x-rows into its LDS region ----
    vf4*       xw4  = (vf4*)xw[w];
    const vf4* xsrc = (const vf4*)(x + ((size_t)bh * cL + i0w) * cD);
    #pragma unroll
    for (int r = 0; r < 8; ++r) xw4[r * 64 + lane] = xsrc[r * 64 + lane];
    // (same wave writes & reads its region: lgkmcnt ordering, no barrier)

    // per-lane store-side constants
    const int xj = (lane * 4) & 31;      // (lane*4+cc)&31 = xj+cc, cc<4
    const int l8 = lane >> 3;            // yj = s*8 + l8

    const float* xrow  = xw[w];
    vf4*         obase = (vf4*)(out + ((size_t)bh * cL + i0w) * cL);

    for (int rp = 0; rp < cRW; rp += 2) {
        // GEMV rows rp, rp+1: two interleaved serial chains, d ascending
        // (exact fmaf order of r5-r11 -> bit-identical lt)
        float a0 = 0.0f, a1 = 0.0f;
        const vf4* xr0 = (const vf4*)(xrow + (rp + 0) * cD);
        const vf4* xr1 = (const vf4*)(xrow + (rp + 1) * cD);
        #pragma unroll
        for (int dq = 0; dq < cD / 4; ++dq) {
            vf4 v0 = xr0[dq];            // all lanes same addr: broadcast
            vf4 v1 = xr1[dq];
            #pragma unroll
            for (int u = 0; u < 4; ++u) {
                a0 = fmaf(v0[u], wreg[dq * 4 + u], a0);
                a1 = fmaf(v1[u], wreg[dq * 4 + u], a1);
            }
        }
        // gather (register shuffle) + 8 fire-and-forget stores
        #pragma unroll
        for (int rr = 0; rr < 2; ++rr) {
            const int   i   = i0w + rp + rr;
            const float acc = rr ? a1 : a0;
            const int   yi  = i >> 5;
            const int   xi  = i & 31;
            const int   bse = xi - xj;
            int cb[4];
            #pragma unroll
            for (int cc = 0; cc < 4; ++cc) cb[cc] = bucket_c(bse - cc);
            #pragma unroll
            for (int s = 0; s < 4; ++s) {
                const int rb = 7 * bucket_c(yi - (s * 8 + l8));
                vf4 o;
                o.x = __shfl(acc, rb + cb[0], 64);
                o.y = __shfl(acc, rb + cb[1], 64);
                o.z = __shfl(acc, rb + cb[2], 64);
                o.w = __shfl(acc, rb + cb[3], 64);
                obase[(size_t)(rp + rr) * (cL / 4) + s * 64 + lane] = o;
            }
        }
    }
}

extern "C" void kernel_launch(void* const* d_in, const int* in_sizes, int n_in,
                              void* d_out, int out_size, void* d_ws, size_t ws_size,
                              hipStream_t stream) {
    const float* x   = (const float*)d_in[0];   // (8,8,1024,64) fp32
    const float* W   = (const float*)d_in[1];   // (8,64,49) fp32
    float*       out = (float*)d_out;           // (8,8,1024,1024) fp32

    const int grid = 64 * 8;                    // 512 blocks, 2 per CU
    irpe_wavestream<<<grid, 256, 0, stream>>>(x, W, out);
}